// Round 4
// baseline (2387.496 us; speedup 1.0000x reference)
//
#include <hip/hip_runtime.h>

// RNN scan: h[t] = tanh(W_h h[t-1] + W_x x[t] + b), out = stacked h.
//  rnn_scan: 256 wgs = 4 per batch chain (wg = q*64+b), 576 thr (8 compute
//  waves + 1 poller wave). WG (b,q) owns rows [128q,128q+128); each compute
//  lane holds its entire W-quarter slice in 64 VGPRs (16 cells).
//  Cross-WG h exchange: kl==0 lanes publish u64 {tag=t+1, 2xf16 h} with sc1
//  (agent scope; round-3 bug was sc0 = workgroup scope -> stale L1 hits).
//  Tag protocol: readers accept a word only when tag == t+1 (equality -> \
//  garbage/stale safe); 2-slot parity buffer; all-to-all step dependency
//  proves tags can only be {stale, t+1}, and slots are never overwritten
//  before all consumers read them (see derivation in session notes).
//  The poller wave validates all 256 u64 of the chain, then stages the 1 KB
//  h-vector into skewed LDS (uint4 idx g+(g>>3), bank-conflict-free, proven
//  round 2); compute waves ds_read it. Global sync traffic: 2.5 KB/WG/step.

typedef _Float16 h2 __attribute__((ext_vector_type(2)));

#define T_STEPS 1024
#define B_SZ    64
#define NIN     128
#define NH      512
#define WCOLS   641        // NH + NIN + 1

__device__ __forceinline__ float fdot2_(h2 a, h2 b, float c) {
#if __has_builtin(__builtin_amdgcn_fdot2)
    return __builtin_amdgcn_fdot2(a, b, c, false);
#else
    return c + (float)a.x * (float)b.x + (float)a.y * (float)b.y;
#endif
}

__device__ __forceinline__ float dot8(uint4 wu, uint4 hu, float acc) {
    union { uint4 u; h2 h[4]; } w, hv;
    w.u = wu; hv.u = hu;
    acc = fdot2_(w.h[0], hv.h[0], acc);
    acc = fdot2_(w.h[1], hv.h[1], acc);
    acc = fdot2_(w.h[2], hv.h[2], acc);
    acc = fdot2_(w.h[3], hv.h[3], acc);
    return acc;
}

__device__ __forceinline__ float fast_tanh(float x) {
    float z = x * 2.8853900817779268f;
#if __has_builtin(__builtin_amdgcn_exp2f)
    float e = __builtin_amdgcn_exp2f(z);
#else
    float e = exp2f(z);
#endif
#if __has_builtin(__builtin_amdgcn_rcpf)
    return 1.f - 2.f * __builtin_amdgcn_rcpf(e + 1.f);
#else
    return 1.f - 2.f / (e + 1.f);
#endif
}

template<int CTRL>
__device__ __forceinline__ float dpp_add(float x) {
    int y = __builtin_amdgcn_update_dpp(0, __builtin_bit_cast(int, x),
                                        CTRL, 0xF, 0xF, true);
    return x + __builtin_bit_cast(float, y);
}
// 0xB1 = quad_perm(1,0,3,2) lane^1; 0x4E = quad_perm(2,3,0,1) lane^2;
// 0x141 = row_half_mirror (i -> 7-i within 8) == xor4 after stages 1,2.

// agent-scope (sc1) memory ops: bypass L1, coherent device-wide.
__device__ __forceinline__ uint4 ld128_sc1(const void* p) {
    uint4 r;
    asm volatile("global_load_dwordx4 %0, %1, off sc1"
                 : "=v"(r) : "v"(p) : "memory");
    return r;
}
__device__ __forceinline__ void st64_sc1(void* p, unsigned long long v) {
    asm volatile("global_store_dwordx2 %0, %1, off sc1"
                 :: "v"(p), "v"(v) : "memory");
}
__device__ __forceinline__ void wait_vm0() {
    asm volatile("s_waitcnt vmcnt(0)" ::: "memory");
    __builtin_amdgcn_sched_barrier(0);   // rule #18: stop hoist past waitcnt
}

// ---------------- prep: weight reshuffle ----------------
__global__ void prep_kernel(const float* __restrict__ w_rec,
                            float* __restrict__ wxT,
                            float* __restrict__ bias,
                            uint4* __restrict__ Whpk) {
    int g = blockIdx.x * 256 + threadIdx.x;
    if (g < NIN * NH) {                               // wxT[i*512+h] = w_x[h][i]
        int i = g >> 9, h = g & (NH - 1);
        wxT[g] = w_rec[h * WCOLS + NH + i];
    } else if (g < NIN * NH + 64 * NH) {              // pack W_h cells to f16
        int m   = g - NIN * NH;                       // 0..32767
        int cg  = m >> 9, tid = m & 511;              // cg = q*16 + c
        int q   = cg >> 4, c = cg & 15;
        int i   = c & 1, j = c >> 1;
        int w   = tid >> 6, lane = tid & 63;
        int rl  = lane >> 3, kl = lane & 7;
        int row = q * 128 + w * 16 + rl * 2 + i;
        int kg  = kl * 8 + j;
        union { uint4 u; _Float16 f[8]; } pk;
#pragma unroll
        for (int e = 0; e < 8; ++e)
            pk.f[e] = (_Float16)w_rec[row * WCOLS + kg * 8 + e];
        Whpk[cg * 512 + tid] = pk.u;
    } else if (g < NIN * NH + 64 * NH + NH) {         // bias
        int h = g - (NIN * NH + 64 * NH);
        bias[h] = w_rec[h * WCOLS + NH + NIN];
    }
}

// ---------------- xin GEMM: u = x @ W_x^T + b -> d_out ----------------
__global__ __launch_bounds__(256) void xin_gemm(const float* __restrict__ x,
                                                const float* __restrict__ wxT,
                                                const float* __restrict__ bias,
                                                float* __restrict__ out) {
    __shared__ float4 xl[128 * 8];
    __shared__ float4 wl[32 * 32];
    __shared__ float  bs[128];
    const int tid = threadIdx.x;
    const int tb0 = blockIdx.x * 128;
    const int hc0 = blockIdx.y * 128;
    if (tid < 128) bs[tid] = bias[hc0 + tid];
    const int tx = tid & 15, ty = tid >> 4;

    float acc[8][8];
#pragma unroll
    for (int r = 0; r < 8; ++r)
#pragma unroll
        for (int c = 0; c < 8; ++c) acc[r][c] = 0.f;

    for (int kc = 0; kc < 4; ++kc) {
        __syncthreads();
#pragma unroll
        for (int l = 0; l < 4; ++l) {
            int idx = tid + 256 * l;
            int row = idx >> 3, c4 = idx & 7;
            xl[idx] = *(const float4*)(x + (long)(tb0 + row) * NIN + kc * 32 + c4 * 4);
        }
#pragma unroll
        for (int l = 0; l < 4; ++l) {
            int idx = tid + 256 * l;
            int ii = idx >> 5, c4 = idx & 31;
            wl[idx] = *(const float4*)(wxT + (kc * 32 + ii) * NH + hc0 + c4 * 4);
        }
        __syncthreads();
#pragma unroll
        for (int i4 = 0; i4 < 8; ++i4) {
            float4 xv[8];
#pragma unroll
            for (int rr = 0; rr < 8; ++rr) xv[rr] = xl[(ty * 8 + rr) * 8 + i4];
#pragma unroll
            for (int j = 0; j < 4; ++j) {
                float4 w0 = wl[(i4 * 4 + j) * 32 + tx * 2];
                float4 w1 = wl[(i4 * 4 + j) * 32 + tx * 2 + 1];
#pragma unroll
                for (int rr = 0; rr < 8; ++rr) {
                    float xs = (j == 0) ? xv[rr].x : (j == 1) ? xv[rr].y
                             : (j == 2) ? xv[rr].z : xv[rr].w;
                    acc[rr][0] += xs * w0.x; acc[rr][1] += xs * w0.y;
                    acc[rr][2] += xs * w0.z; acc[rr][3] += xs * w0.w;
                    acc[rr][4] += xs * w1.x; acc[rr][5] += xs * w1.y;
                    acc[rr][6] += xs * w1.z; acc[rr][7] += xs * w1.w;
                }
            }
        }
    }
#pragma unroll
    for (int rr = 0; rr < 8; ++rr) {
        long row = tb0 + ty * 8 + rr;
        float4 o0, o1;
        o0.x = acc[rr][0] + bs[tx * 8 + 0]; o0.y = acc[rr][1] + bs[tx * 8 + 1];
        o0.z = acc[rr][2] + bs[tx * 8 + 2]; o0.w = acc[rr][3] + bs[tx * 8 + 3];
        o1.x = acc[rr][4] + bs[tx * 8 + 4]; o1.y = acc[rr][5] + bs[tx * 8 + 5];
        o1.z = acc[rr][6] + bs[tx * 8 + 6]; o1.w = acc[rr][7] + bs[tx * 8 + 7];
        *(float4*)(out + row * NH + hc0 + tx * 8)     = o0;
        *(float4*)(out + row * NH + hc0 + tx * 8 + 4) = o1;
    }
}

// ---------------- scan: 4 WGs/chain, tag-verified exchange ----------------
__global__ __launch_bounds__(576, 2) void rnn_scan(float* __restrict__ out,
                                                   const float* __restrict__ h0,
                                                   const uint4* __restrict__ Whpk,
                                                   unsigned long long* __restrict__ hx2) {
    __shared__ int  lds_pad[20484];    // ~80 KiB -> 1 WG/CU
    __shared__ uint4 hh[2][72];        // double-buffered f16 h, skewed

    const int tid = threadIdx.x, wg = blockIdx.x;
    const int b = wg & 63, q = wg >> 6;
    const int w = tid >> 6, lane = tid & 63, rl = lane >> 3, kl = lane & 7;
    ((volatile int*)lds_pad)[tid] = 0;   // keep pad allocated

    uint4 Wreg[16];
    if (tid < 512) {
#pragma unroll
        for (int c = 0; c < 16; ++c) Wreg[c] = Whpk[(q * 16 + c) * 512 + tid];
    }

    // h0 -> hh[0] (f16, skewed: granule g at uint4 index g + (g>>3))
    if (tid < 512) {
        int g = tid >> 3, e = tid & 7;
        _Float16* p = (_Float16*)&hh[0][g + (g >> 3)];
        p[e] = (_Float16)h0[b * NH + tid];
    }

    const int rowpair = q * 128 + w * 16 + rl * 2;
    const int rpo = q * 64 + w * 8 + rl;            // owned row-pair index
    float* pu = out + (long)b * NH + rowpair;
    float2 u_cur = make_float2(0.f, 0.f);
    if (tid < 512 && kl == 0) u_cur = *(const float2*)pu;
    unsigned long long* const hxb = hx2 + b * 256;  // chain base

    __syncthreads();

    for (int t = 0; t < T_STEPS; ++t) {
        if (tid < 512) {
            // ------- compute wave -------
            const uint4* hc = hh[t & 1];
            uint4 hsv[8];
#pragma unroll
            for (int j = 0; j < 8; ++j) hsv[j] = hc[9 * kl + j];

            float a00 = 0.f, a01 = 0.f, a10 = 0.f, a11 = 0.f;
#pragma unroll
            for (int j = 0; j < 8; j += 2) {
                a00 = dot8(Wreg[j * 2 + 0], hsv[j],     a00);
                a10 = dot8(Wreg[j * 2 + 1], hsv[j],     a10);
                a01 = dot8(Wreg[j * 2 + 2], hsv[j + 1], a01);
                a11 = dot8(Wreg[j * 2 + 3], hsv[j + 1], a11);
            }
            float acc0 = a00 + a01, acc1 = a10 + a11;
            acc0 = dpp_add<0xB1>(acc0); acc0 = dpp_add<0x4E>(acc0); acc0 = dpp_add<0x141>(acc0);
            acc1 = dpp_add<0xB1>(acc1); acc1 = dpp_add<0x4E>(acc1); acc1 = dpp_add<0x141>(acc1);

            if (kl == 0) {
                long stride = (t + 1 < T_STEPS) ? (long)B_SZ * NH : 0;
                float2 u_nxt = *(const float2*)(pu + stride);
                float hv0 = fast_tanh(acc0 + u_cur.x);
                float hv1 = fast_tanh(acc1 + u_cur.y);
                *(float2*)pu = make_float2(hv0, hv1);      // fp32 output
                h2 hp; hp.x = (_Float16)hv0; hp.y = (_Float16)hv1;
                unsigned long long pk =
                    ((unsigned long long)(unsigned)(t + 1) << 32)
                    | (unsigned long long)__builtin_bit_cast(unsigned int, hp);
                st64_sc1(hxb + ((t + 1) & 1) * 16384 + rpo, pk);
                u_cur = u_nxt;
            }
            pu += (long)B_SZ * NH;
        } else if (t + 1 < T_STEPS) {
            // ------- poller wave: validate chain h(t+1), stage to LDS -------
            const int L = tid - 512;                   // 0..63
            const unsigned want = (unsigned)(t + 1);
            const char* src = (const char*)(hxb + ((t + 1) & 1) * 16384) + L * 32;
            uint4 va = ld128_sc1(src);
            uint4 vb = ld128_sc1(src + 16);
            wait_vm0();
            for (;;) {
                int ok = (va.y == want) & (va.w == want) &
                         (vb.y == want) & (vb.w == want);
                if (__all(ok)) break;
                if (va.y != want || va.w != want) va = ld128_sc1(src);
                if (vb.y != want || vb.w != want) vb = ld128_sc1(src + 16);
                wait_vm0();
            }
            hh[(t + 1) & 1][L + (L >> 3)] = make_uint4(va.x, va.z, vb.x, vb.z);
        }
        if (t + 1 == T_STEPS) break;
        __syncthreads();   // h(t+1) staged; hh[t&1] reads complete
    }
}

extern "C" void kernel_launch(void* const* d_in, const int* in_sizes, int n_in,
                              void* d_out, int out_size, void* d_ws, size_t ws_size,
                              hipStream_t stream) {
    const float* x     = (const float*)d_in[0];   // (1024,64,128)
    const float* h0    = (const float*)d_in[1];   // (64,512)
    const float* w_rec = (const float*)d_in[2];   // (512,641)
    float* out = (float*)d_out;                   // (1024,64,512)

    // ws: wxT 256K (aliased by hx2 256K during scan) | bias 2K | Whpk 512K
    float* wxT  = (float*)d_ws;
    float* bias = wxT + NIN * NH;
    uint4* Whpk = (uint4*)((char*)d_ws + (NIN * NH + NH) * sizeof(float));
    unsigned long long* hx2 = (unsigned long long*)d_ws;  // 2 slots x 64 x 256 u64

    prep_kernel<<<386, 256, 0, stream>>>(w_rec, wxT, bias, Whpk);

    dim3 gA(T_STEPS * B_SZ / 128, NH / 128);      // 512 x 4
    xin_gemm<<<gA, 256, 0, stream>>>(x, wxT, bias, out);

    void* args[] = { (void*)&out, (void*)&h0, (void*)&Whpk, (void*)&hx2 };
    if (hipLaunchCooperativeKernel((const void*)rnn_scan, dim3(256), dim3(576),
                                   args, 0, stream) != hipSuccess) {
        // fallback: 256 WGs on 256 CUs, 1 WG/CU via LDS pad -> co-resident
        rnn_scan<<<256, 576, 0, stream>>>(out, h0, Whpk, hx2);
    }
}

// Round 6
// 1687.555 us; speedup vs baseline: 1.4148x; 1.4148x over previous
//
#include <hip/hip_runtime.h>

// RNN scan: h[t] = tanh(W_h h[t-1] + W_x x[t] + b), out = stacked h.
//  Structure = round-2 PROVEN kernel (one WG per chain, coop h-read, DPP
//  reduce), with the W-residency fixed:
//   - 48 of 64 cells in REGISTERS (192 VGPR), loaded via inline-asm
//     global_load_dwordx4 into NAMED variables -> the compiler cannot
//     rematerialize/sink them into the t-loop (round-2 counters showed
//     VGPR=128: plain loads were partially remat'd; round-5's "+v" pin
//     didn't compile - tied indirect unsupported; "=v" outputs do).
//   - 16 cells (j=6,7) in LDS (128 KiB).
//   - NO L2 stream (round-2 streamed 16 cells/step: ~2200 cyc VMEM return
//     + addressing VALU, now eliminated).
//  Lane layout per wave (round-2, verified absmax 0.0039): lane = rl*8+kl;
//  kl owns k-slice [64kl,64kl+64); acc[i] = row 64w+8i+rl partial; DPP
//  butterfly over 8 kl lanes; lane finalizes row own = 64w+8kl+rl.
//  h double-buffered in LDS, skewed (uint4 idx g+(g>>3)), conflict-free.

typedef _Float16 h2 __attribute__((ext_vector_type(2)));

#define T_STEPS 1024
#define B_SZ    64
#define NIN     128
#define NH      512
#define WCOLS   641        // NH + NIN + 1
// cell c = j*8 + i: j = k-subgroup (8 f16), i = row index (acc chain).
// cells 0..47 (j=0..5): registers; cells 48..63 (j=6..7): LDS.

__device__ __forceinline__ float fdot2_(h2 a, h2 b, float c) {
#if __has_builtin(__builtin_amdgcn_fdot2)
    return __builtin_amdgcn_fdot2(a, b, c, false);
#else
    return c + (float)a.x * (float)b.x + (float)a.y * (float)b.y;
#endif
}

__device__ __forceinline__ float dot8(uint4 wu, uint4 hu, float acc) {
    union { uint4 u; h2 h[4]; } w, hv;
    w.u = wu; hv.u = hu;
    acc = fdot2_(w.h[0], hv.h[0], acc);
    acc = fdot2_(w.h[1], hv.h[1], acc);
    acc = fdot2_(w.h[2], hv.h[2], acc);
    acc = fdot2_(w.h[3], hv.h[3], acc);
    return acc;
}

__device__ __forceinline__ float fast_tanh(float x) {
    float z = x * 2.8853900817779268f;
#if __has_builtin(__builtin_amdgcn_exp2f)
    float e = __builtin_amdgcn_exp2f(z);
#else
    float e = exp2f(z);
#endif
#if __has_builtin(__builtin_amdgcn_rcpf)
    return 1.f - 2.f * __builtin_amdgcn_rcpf(e + 1.f);
#else
    return 1.f - 2.f / (e + 1.f);
#endif
}

template<int CTRL>
__device__ __forceinline__ float dpp_add(float x) {
    int y = __builtin_amdgcn_update_dpp(0, __builtin_bit_cast(int, x),
                                        CTRL, 0xF, 0xF, true);
    return x + __builtin_bit_cast(float, y);
}
// 0xB1 = quad_perm(1,0,3,2) lane^1; 0x4E = quad_perm(2,3,0,1) lane^2;
// 0x141 = row_half_mirror (i -> 7-i within 8) == xor4 after stages 1,2.

// ---------------- prep: weight reshuffle (round-2-proven layout) ----------------
__global__ void prep_kernel(const float* __restrict__ w_rec,
                            float* __restrict__ wxT,
                            float* __restrict__ bias,
                            uint4* __restrict__ Whpk) {
    int g = blockIdx.x * 256 + threadIdx.x;
    if (g < NIN * NH) {                               // wxT[i*512+h] = w_x[h][i]
        int i = g >> 9, h = g & (NH - 1);
        wxT[g] = w_rec[h * WCOLS + NH + i];
    } else if (g < NIN * NH + 64 * NH) {              // pack W_h cells to f16
        int m   = g - NIN * NH;                       // 0..32767
        int c   = m >> 9, tid = m & 511;
        int w   = tid >> 6, lane = tid & 63;
        int rl  = lane >> 3, kl = lane & 7;
        int i   = c & 7, j = c >> 3;
        int row = w * 64 + i * 8 + rl;
        int kg  = kl * 8 + j;                         // global k-group 0..63
        union { uint4 u; _Float16 f[8]; } pk;
#pragma unroll
        for (int e = 0; e < 8; ++e)
            pk.f[e] = (_Float16)w_rec[row * WCOLS + kg * 8 + e];
        Whpk[c * 512 + tid] = pk.u;
    } else if (g < NIN * NH + 64 * NH + NH) {         // bias
        int h = g - (NIN * NH + 64 * NH);
        bias[h] = w_rec[h * WCOLS + NH + NIN];
    }
}

// ---------------- xin GEMM: u = x @ W_x^T + b -> d_out ----------------
__global__ __launch_bounds__(256) void xin_gemm(const float* __restrict__ x,
                                                const float* __restrict__ wxT,
                                                const float* __restrict__ bias,
                                                float* __restrict__ out) {
    __shared__ float4 xl[128 * 8];
    __shared__ float4 wl[32 * 32];
    __shared__ float  bs[128];
    const int tid = threadIdx.x;
    const int tb0 = blockIdx.x * 128;
    const int hc0 = blockIdx.y * 128;
    if (tid < 128) bs[tid] = bias[hc0 + tid];
    const int tx = tid & 15, ty = tid >> 4;

    float acc[8][8];
#pragma unroll
    for (int r = 0; r < 8; ++r)
#pragma unroll
        for (int c = 0; c < 8; ++c) acc[r][c] = 0.f;

    for (int kc = 0; kc < 4; ++kc) {
        __syncthreads();
#pragma unroll
        for (int l = 0; l < 4; ++l) {
            int idx = tid + 256 * l;
            int row = idx >> 3, c4 = idx & 7;
            xl[idx] = *(const float4*)(x + (long)(tb0 + row) * NIN + kc * 32 + c4 * 4);
        }
#pragma unroll
        for (int l = 0; l < 4; ++l) {
            int idx = tid + 256 * l;
            int ii = idx >> 5, c4 = idx & 31;
            wl[idx] = *(const float4*)(wxT + (kc * 32 + ii) * NH + hc0 + c4 * 4);
        }
        __syncthreads();
#pragma unroll
        for (int i4 = 0; i4 < 8; ++i4) {
            float4 xv[8];
#pragma unroll
            for (int rr = 0; rr < 8; ++rr) xv[rr] = xl[(ty * 8 + rr) * 8 + i4];
#pragma unroll
            for (int j = 0; j < 4; ++j) {
                float4 w0 = wl[(i4 * 4 + j) * 32 + tx * 2];
                float4 w1 = wl[(i4 * 4 + j) * 32 + tx * 2 + 1];
#pragma unroll
                for (int rr = 0; rr < 8; ++rr) {
                    float xs = (j == 0) ? xv[rr].x : (j == 1) ? xv[rr].y
                             : (j == 2) ? xv[rr].z : xv[rr].w;
                    acc[rr][0] += xs * w0.x; acc[rr][1] += xs * w0.y;
                    acc[rr][2] += xs * w0.z; acc[rr][3] += xs * w0.w;
                    acc[rr][4] += xs * w1.x; acc[rr][5] += xs * w1.y;
                    acc[rr][6] += xs * w1.z; acc[rr][7] += xs * w1.w;
                }
            }
        }
    }
#pragma unroll
    for (int rr = 0; rr < 8; ++rr) {
        long row = tb0 + ty * 8 + rr;
        float4 o0, o1;
        o0.x = acc[rr][0] + bs[tx * 8 + 0]; o0.y = acc[rr][1] + bs[tx * 8 + 1];
        o0.z = acc[rr][2] + bs[tx * 8 + 2]; o0.w = acc[rr][3] + bs[tx * 8 + 3];
        o1.x = acc[rr][4] + bs[tx * 8 + 4]; o1.y = acc[rr][5] + bs[tx * 8 + 5];
        o1.z = acc[rr][6] + bs[tx * 8 + 6]; o1.w = acc[rr][7] + bs[tx * 8 + 7];
        *(float4*)(out + row * NH + hc0 + tx * 8)     = o0;
        *(float4*)(out + row * NH + hc0 + tx * 8 + 4) = o1;
    }
}

// ---------------- serial scan: one WG per batch element ----------------
__global__ __launch_bounds__(512, 2) void rnn_scan(float* __restrict__ out,
                                                   const float* __restrict__ h0,
                                                   const uint4* __restrict__ Whpk) {
    __shared__ uint4 Wl[16 * 512];   // cells 48..63 (j=6,7), 128 KiB
    __shared__ uint4 hh[2][72];      // double-buffered f16 h, skewed, 2.25 KiB

    const int tid = threadIdx.x, b = blockIdx.x;
    const int w = tid >> 6, lane = tid & 63, rl = lane >> 3, kl = lane & 7;

#pragma unroll
    for (int c = 0; c < 16; ++c) Wl[c * 512 + tid] = Whpk[(48 + c) * 512 + tid];

    // 48 register cells, asm-loaded into NAMED vars: non-rematerializable,
    // non-sinkable ("=v" output constraint compiles; "+v" tied does not).
#define LOADW(n) uint4 W##n; { const uint4* p_ = Whpk + (n) * 512 + tid;      \
    asm volatile("global_load_dwordx4 %0, %1, off" : "=v"(W##n) : "v"(p_)); }
    LOADW(0)  LOADW(1)  LOADW(2)  LOADW(3)  LOADW(4)  LOADW(5)  LOADW(6)  LOADW(7)
    LOADW(8)  LOADW(9)  LOADW(10) LOADW(11) LOADW(12) LOADW(13) LOADW(14) LOADW(15)
    LOADW(16) LOADW(17) LOADW(18) LOADW(19) LOADW(20) LOADW(21) LOADW(22) LOADW(23)
    LOADW(24) LOADW(25) LOADW(26) LOADW(27) LOADW(28) LOADW(29) LOADW(30) LOADW(31)
    LOADW(32) LOADW(33) LOADW(34) LOADW(35) LOADW(36) LOADW(37) LOADW(38) LOADW(39)
    LOADW(40) LOADW(41) LOADW(42) LOADW(43) LOADW(44) LOADW(45) LOADW(46) LOADW(47)
#undef LOADW
    asm volatile("s_waitcnt vmcnt(0)" ::: "memory");
    __builtin_amdgcn_sched_barrier(0);   // rule #18: no hoist past the waitcnt

    // h0 -> hh[0] (f16, skewed: group g at uint4 index g + (g>>3))
    {
        int g = tid >> 3, e = tid & 7;
        ((_Float16*)&hh[0][g + (g >> 3)])[e] = (_Float16)h0[b * NH + tid];
    }
    __syncthreads();

    const int own = w * 64 + kl * 8 + rl;     // row this lane finalizes
    float* pu = out + (long)b * NH + own;
    float u_cur = *pu;                        // u for t=0

    for (int t = 0; t < T_STEPS; ++t) {
        const uint4* hc = hh[t & 1];

        // next-u prefetch (VMEM, overlaps dots)
        long stride = (t + 1 < T_STEPS) ? (long)B_SZ * NH : 0;
        float u_nxt = pu[stride];

        // cooperative h read: lane's 8 k-groups (8kl+j), skewed idx 9kl+j
        uint4 hs[8];
#pragma unroll
        for (int j = 0; j < 8; ++j) hs[j] = hc[9 * kl + j];

        float acc[8];
#pragma unroll
        for (int i = 0; i < 8; ++i) acc[i] = 0.f;

        // register cells: c = j*8+i -> acc[c&7] over hs[c>>3]
#define DOTW(n) acc[(n) & 7] = dot8(W##n, hs[(n) >> 3], acc[(n) & 7]);
        DOTW(0)  DOTW(1)  DOTW(2)  DOTW(3)  DOTW(4)  DOTW(5)  DOTW(6)  DOTW(7)
        DOTW(8)  DOTW(9)  DOTW(10) DOTW(11) DOTW(12) DOTW(13) DOTW(14) DOTW(15)
        DOTW(16) DOTW(17) DOTW(18) DOTW(19) DOTW(20) DOTW(21) DOTW(22) DOTW(23)
        DOTW(24) DOTW(25) DOTW(26) DOTW(27) DOTW(28) DOTW(29) DOTW(30) DOTW(31)
        DOTW(32) DOTW(33) DOTW(34) DOTW(35) DOTW(36) DOTW(37) DOTW(38) DOTW(39)
        DOTW(40) DOTW(41) DOTW(42) DOTW(43) DOTW(44) DOTW(45) DOTW(46) DOTW(47)
#undef DOTW

        // LDS cells 48..63: j = 6 + (c>>3), i = c&7
#pragma unroll
        for (int c = 0; c < 16; ++c)
            acc[c & 7] = dot8(Wl[c * 512 + tid], hs[6 + (c >> 3)], acc[c & 7]);

        // reduce across the 8 kl lanes (pure-VALU DPP butterfly)
#pragma unroll
        for (int i = 0; i < 8; ++i) {
            acc[i] = dpp_add<0xB1>(acc[i]);
            acc[i] = dpp_add<0x4E>(acc[i]);
            acc[i] = dpp_add<0x141>(acc[i]);
        }

        // lane owns row 64w + 8kl + rl -> select acc[kl]
        float a01 = (kl & 1) ? acc[1] : acc[0];
        float a23 = (kl & 1) ? acc[3] : acc[2];
        float a45 = (kl & 1) ? acc[5] : acc[4];
        float a67 = (kl & 1) ? acc[7] : acc[6];
        float b03 = (kl & 2) ? a23 : a01;
        float b47 = (kl & 2) ? a67 : a45;
        float sel = (kl & 4) ? b47 : b03;

        float hnew = fast_tanh(sel + u_cur);
        u_cur = u_nxt;
        *pu = hnew;                                   // fp32 output (in place)
        ((_Float16*)&hh[(t + 1) & 1][9 * w + kl])[rl] = (_Float16)hnew;
        pu += (long)B_SZ * NH;

        if (t + 1 == T_STEPS) break;
        __syncthreads();   // writes to hh[(t+1)&1] visible; reads of hc done
    }
}

extern "C" void kernel_launch(void* const* d_in, const int* in_sizes, int n_in,
                              void* d_out, int out_size, void* d_ws, size_t ws_size,
                              hipStream_t stream) {
    const float* x     = (const float*)d_in[0];   // (1024,64,128)
    const float* h0    = (const float*)d_in[1];   // (64,512)
    const float* w_rec = (const float*)d_in[2];   // (512,641)
    float* out = (float*)d_out;                   // (1024,64,512)

    // ws: wxT 256K | bias 2K | Whpk 512K
    float* wxT  = (float*)d_ws;
    float* bias = wxT + NIN * NH;
    uint4* Whpk = (uint4*)((char*)d_ws + (NIN * NH + NH) * sizeof(float));

    prep_kernel<<<387, 256, 0, stream>>>(w_rec, wxT, bias, Whpk);

    dim3 gA(T_STEPS * B_SZ / 128, NH / 128);      // 512 x 4
    xin_gemm<<<gA, 256, 0, stream>>>(x, wxT, bias, out);

    rnn_scan<<<B_SZ, NH, 0, stream>>>(out, h0, Whpk);
}